// Round 4
// baseline (800.741 us; speedup 1.0000x reference)
//
#include <hip/hip_runtime.h>
#include <math.h>

#define HW 36864
#define CD 192
#define NH 6
#define HDIM 32
#define HIDD 768

typedef unsigned short u16;
typedef __attribute__((ext_vector_type(8))) short bf16x8;
typedef __attribute__((ext_vector_type(4))) float f32x4;

__device__ __forceinline__ float gelu_f(float x) {
  return 0.5f * x * (1.0f + erff(x * 0.70710678118654752f));
}
__device__ __forceinline__ u16 f2b(float f) {
  union { float f; unsigned u; } v; v.f = f;
  unsigned r = v.u + 0x7fff + ((v.u >> 16) & 1);   // RNE
  return (u16)(r >> 16);
}
__device__ __forceinline__ float b2f(u16 b) {
  union { unsigned u; float f; } v; v.u = ((unsigned)b) << 16;
  return v.f;
}
__device__ __forceinline__ float b2f_lo(unsigned u) {
  union { unsigned x; float f; } v; v.x = u << 16; return v.f;
}
__device__ __forceinline__ float b2f_hi(unsigned u) {
  union { unsigned x; float f; } v; v.x = u & 0xffff0000u; return v.f;
}

// ---------- fused LayerNorm + transpose: fp32 CM in -> bf16 TM out ----------
__global__ __launch_bounds__(256)
void lnt_kernel(const float* __restrict__ in, const float* __restrict__ g,
                const float* __restrict__ b, u16* __restrict__ outTM)
{
  __shared__ float tile[64][193];
  __shared__ float red[64][8];
  __shared__ float2 stat2[64];
  __shared__ float gb[384];
  const int tid = threadIdx.x;
  const int part = tid >> 6, tk = tid & 63;
  const int tok = blockIdx.x * 64 + tk;
  if (tid < 192) { gb[tid] = g[tid]; gb[192 + tid] = b[tid]; }
  float s = 0.f, sq = 0.f;
  for (int c = part * 48; c < part * 48 + 48; ++c) {
    float v = in[(size_t)c * HW + tok];
    tile[tk][c] = v; s += v; sq += v * v;
  }
  red[tk][part] = s; red[tk][4 + part] = sq;
  __syncthreads();
  if (tid < 64) {
    float ss = red[tid][0] + red[tid][1] + red[tid][2] + red[tid][3];
    float qq = red[tid][4] + red[tid][5] + red[tid][6] + red[tid][7];
    float m = ss * (1.0f / CD);
    float var = fmaxf(qq * (1.0f / CD) - m * m, 0.f);
    stat2[tid] = make_float2(m, rsqrtf(var + 1e-5f));
  }
  __syncthreads();
  unsigned* op = (unsigned*)outTM + (size_t)blockIdx.x * 6144;
  #pragma unroll
  for (int r = 0; r < 24; ++r) {
    int idx = tid + r * 256;
    int tok2 = idx / 96, dc = idx - tok2 * 96;
    float2 st = stat2[tok2];
    int c = dc * 2;
    float v0 = (tile[tok2][c] - st.x) * st.y * gb[c] + gb[192 + c];
    float v1 = (tile[tok2][c + 1] - st.x) * st.y * gb[c + 1] + gb[192 + c + 1];
    op[idx] = (unsigned)f2b(v0) | ((unsigned)f2b(v1) << 16);
  }
}

// ---------- weight prep: fp32 [K][N] -> bf16 [N][K] ----------
__global__ __launch_bounds__(256)
void wtrans_kernel(const float* __restrict__ in, u16* __restrict__ out, int K, int N)
{
  __shared__ float ls[32][33];
  const int k0 = blockIdx.x * 32, n0 = blockIdx.y * 32;
  const int t = threadIdx.x;
  #pragma unroll
  for (int r = 0; r < 4; ++r) {
    int idx = t + r * 256;
    int k = idx >> 5, n = idx & 31;
    ls[k][n] = in[(size_t)(k0 + k) * N + n0 + n];
  }
  __syncthreads();
  #pragma unroll
  for (int r = 0; r < 4; ++r) {
    int idx = t + r * 256;
    int n = idx >> 5, k = idx & 31;
    out[(size_t)(n0 + n) * K + k0 + k] = f2b(ls[k][n]);
  }
}

__global__ __launch_bounds__(256)
void wtrans4_kernel(const float* __restrict__ w0, const float* __restrict__ w1,
                    const float* __restrict__ w2, const float* __restrict__ w3,
                    u16* __restrict__ out)
{
  __shared__ float ls[32][33];
  const int z = blockIdx.z;
  const float* in = (z == 0) ? w0 : (z == 1 ? w1 : (z == 2 ? w2 : w3));
  u16* op = out + (size_t)z * CD * CD;
  const int k0 = blockIdx.x * 32, n0 = blockIdx.y * 32;
  const int t = threadIdx.x;
  #pragma unroll
  for (int r = 0; r < 4; ++r) {
    int idx = t + r * 256;
    int k = idx >> 5, n = idx & 31;
    ls[k][n] = in[(size_t)(k0 + k) * CD + n0 + n];
  }
  __syncthreads();
  #pragma unroll
  for (int r = 0; r < 4; ++r) {
    int idx = t + r * 256;
    int n = idx >> 5, k = idx & 31;
    op[(size_t)(n0 + n) * CD + k0 + k] = f2b(ls[k][n]);
  }
}

// ---------- rpb pre-gather: rpbg[h][i][j] = rpb_table[rpi[i][j]][h] ----------
__global__ __launch_bounds__(256)
void rpbg_kernel(const int* __restrict__ rpi, const float* __restrict__ rpb_t,
                 float* __restrict__ out)
{
  const int i = blockIdx.x, j = threadIdx.x;
  const int r = rpi[i * 256 + j];
  #pragma unroll
  for (int h = 0; h < NH; ++h)
    out[(size_t)h * 65536 + i * 256 + j] = rpb_t[r * NH + h];
}

// ---------- bf16 MFMA GEMM (padded LDS stride 40: bank-conflict-free frags) ----------
// MODE 0: QKV  -> bf16 CM out, +bias, q-segment scaled
// MODE 1: PROJ -> fp32 CM out, +bias +aux (fp32 CM)
// MODE 2: FC1  -> bf16 CM out, +bias, GELU
// MODE 3: FC2  -> fp32 TM out, +bias +aux (fp32 CM)
template<int MODE>
__global__ __launch_bounds__(256, 4)
void mgemm_kernel(const u16* __restrict__ A,
                  const u16* __restrict__ W0, const u16* __restrict__ W1, const u16* __restrict__ W2,
                  const float* __restrict__ b0, const float* __restrict__ b1, const float* __restrict__ b2,
                  const float* __restrict__ aux, void* __restrict__ outv,
                  int K, int segN)
{
  const int n0 = blockIdx.x * 64;
  const int m0 = blockIdx.y * 128;
  const int seg = n0 / segN;
  const u16* Wp = (seg == 0) ? W0 : (seg == 1 ? W1 : W2);
  const float* biasp = (seg == 0) ? b0 : (seg == 1 ? b1 : b2);
  const int nl0 = n0 - seg * segN;

  __shared__ u16 As[128 * 40];
  __shared__ u16 Bs[64 * 40];

  const int tid = threadIdx.x;
  const int lane = tid & 63, wave = tid >> 6;
  const int wm = (wave >> 1) * 64, wn = (wave & 1) * 32;
  const int fm = lane & 15, fq = lane >> 4;
  const int ar = tid >> 2, akq = tid & 3;

  f32x4 acc[4][2];
  #pragma unroll
  for (int i = 0; i < 4; ++i) { acc[i][0] = (f32x4)(0.f); acc[i][1] = (f32x4)(0.f); }

  uint4 rA0, rA1, rB, nA0, nA1, nB;
  rA0 = *(const uint4*)(A + (size_t)(m0 + ar) * K + akq * 8);
  rA1 = *(const uint4*)(A + (size_t)(m0 + ar + 64) * K + akq * 8);
  rB  = *(const uint4*)(Wp + (size_t)(nl0 + ar) * K + akq * 8);

  for (int k0 = 0; k0 < K; k0 += 32) {
    *(uint4*)(&As[ar * 40 + akq * 8]) = rA0;
    *(uint4*)(&As[(ar + 64) * 40 + akq * 8]) = rA1;
    *(uint4*)(&Bs[ar * 40 + akq * 8]) = rB;
    __syncthreads();
    const int kn = (k0 + 32 < K) ? k0 + 32 : k0;
    nA0 = *(const uint4*)(A + (size_t)(m0 + ar) * K + kn + akq * 8);
    nA1 = *(const uint4*)(A + (size_t)(m0 + ar + 64) * K + kn + akq * 8);
    nB  = *(const uint4*)(Wp + (size_t)(nl0 + ar) * K + kn + akq * 8);
    bf16x8 af[4], bf[2];
    #pragma unroll
    for (int mt = 0; mt < 4; ++mt)
      af[mt] = *(const bf16x8*)(&As[(wm + mt * 16 + fm) * 40 + fq * 8]);
    #pragma unroll
    for (int nt = 0; nt < 2; ++nt)
      bf[nt] = *(const bf16x8*)(&Bs[(wn + nt * 16 + fm) * 40 + fq * 8]);
    #pragma unroll
    for (int mt = 0; mt < 4; ++mt)
      #pragma unroll
      for (int nt = 0; nt < 2; ++nt)
        acc[mt][nt] = __builtin_amdgcn_mfma_f32_16x16x32_bf16(af[mt], bf[nt], acc[mt][nt], 0, 0, 0);
    __syncthreads();
    rA0 = nA0; rA1 = nA1; rB = nB;
  }

  #pragma unroll
  for (int nt = 0; nt < 2; ++nt) {
    const int n = n0 + wn + nt * 16 + fm;
    const float bia = biasp[nl0 + wn + nt * 16 + fm];
    #pragma unroll
    for (int mt = 0; mt < 4; ++mt) {
      const int mb = m0 + wm + mt * 16 + fq * 4;
      float o[4];
      #pragma unroll
      for (int r = 0; r < 4; ++r) o[r] = acc[mt][nt][r] + bia;
      if (MODE == 0) {
        const float sc = (seg == 0) ? 0.17677669529663689f : 1.0f;
        u16 h0 = f2b(o[0] * sc), h1 = f2b(o[1] * sc), h2 = f2b(o[2] * sc), h3 = f2b(o[3] * sc);
        uint2 pk = make_uint2((unsigned)h0 | ((unsigned)h1 << 16), (unsigned)h2 | ((unsigned)h3 << 16));
        *(uint2*)((u16*)outv + (size_t)n * HW + mb) = pk;
      } else if (MODE == 1) {
        const float4 ax = *(const float4*)(aux + (size_t)n * HW + mb);
        *(float4*)((float*)outv + (size_t)n * HW + mb) =
            make_float4(o[0] + ax.x, o[1] + ax.y, o[2] + ax.z, o[3] + ax.w);
      } else if (MODE == 2) {
        u16 h0 = f2b(gelu_f(o[0])), h1 = f2b(gelu_f(o[1]));
        u16 h2 = f2b(gelu_f(o[2])), h3 = f2b(gelu_f(o[3]));
        uint2 pk = make_uint2((unsigned)h0 | ((unsigned)h1 << 16), (unsigned)h2 | ((unsigned)h3 << 16));
        *(uint2*)((u16*)outv + (size_t)n * HW + mb) = pk;
      } else {
        const float4 ax = *(const float4*)(aux + (size_t)n * HW + mb);
        float* op = (float*)outv;
        op[(size_t)(mb + 0) * CD + n] = o[0] + ax.x;
        op[(size_t)(mb + 1) * CD + n] = o[1] + ax.y;
        op[(size_t)(mb + 2) * CD + n] = o[2] + ax.z;
        op[(size_t)(mb + 3) * CD + n] = o[3] + ax.w;
      }
    }
  }
}

// ---------- depthwise 5x5 + GELU (+residual), 32 planes/block, TM output ----------
// in: bf16 CM [PL][HW]; out: bf16 TM [HW][PL]. Register-blocked rows: 3 LDS b32
// reads per (plane,row) feed 10 FMAs; coalesced 64B TM writes per pixel.
template<bool ADD>
__global__ __launch_bounds__(256)
void dwconv_tm_kernel(const u16* __restrict__ in, const float* __restrict__ w,
                      const float* __restrict__ bias, u16* __restrict__ out, int PL)
{
  const int p0 = blockIdx.z * 32;
  const int bx = blockIdx.x * 64, by = blockIdx.y * 4;
  __shared__ u16 tile[32 * 546];       // plane stride 546 (==2 mod 16: pg-lanes conflict-free)
  __shared__ float ws[32][26];
  const int tid = threadIdx.x;
  for (int e = tid; e < 832; e += 256) {
    int p = e / 26, q = e - p * 26;
    ws[p][q] = (q < 25) ? w[(p0 + p) * 25 + q] : bias[p0 + p];
  }
  for (int e = tid; e < 256 * 34; e += 256) {
    int rp = e / 34, ch = e - rp * 34;
    int p = rp >> 3, r = rp & 7;
    int gy = by + r - 2, gx = bx + ch * 2 - 2;
    unsigned val = 0;
    if (gy >= 0 && gy < 192 && gx >= 0 && gx < 192)
      val = *(const unsigned*)(in + (size_t)(p0 + p) * HW + gy * 192 + gx);
    *(unsigned*)&tile[p * 546 + r * 68 + ch * 2] = val;
  }
  __syncthreads();
  const int txp = tid >> 3, pg = tid & 7;   // col-pair, plane-quad
  u16 res[4][2][4];                         // [pp][col][row]
  #pragma unroll
  for (int pp = 0; pp < 4; ++pp) {
    const int p = pg * 4 + pp;
    const u16* tp = &tile[p * 546];
    float o0[4] = {0.f, 0.f, 0.f, 0.f}, o1[4] = {0.f, 0.f, 0.f, 0.f};
    #pragma unroll
    for (int ir = 0; ir < 8; ++ir) {
      const unsigned* rowp = (const unsigned*)(tp + ir * 68 + txp * 2);
      unsigned ua = rowp[0], ub = rowp[1], uc = rowp[2];
      float f0 = b2f_lo(ua), f1 = b2f_hi(ua), f2 = b2f_lo(ub);
      float f3 = b2f_hi(ub), f4 = b2f_lo(uc), f5 = b2f_hi(uc);
      #pragma unroll
      for (int dy = 0; dy < 5; ++dy) {
        const int r = ir - dy;
        if (r >= 0 && r < 4) {
          const float w0 = ws[p][dy * 5 + 0], w1 = ws[p][dy * 5 + 1], w2 = ws[p][dy * 5 + 2];
          const float w3 = ws[p][dy * 5 + 3], w4 = ws[p][dy * 5 + 4];
          o0[r] += f0 * w0 + f1 * w1 + f2 * w2 + f3 * w3 + f4 * w4;
          o1[r] += f1 * w0 + f2 * w1 + f3 * w2 + f4 * w3 + f5 * w4;
        }
      }
    }
    const float bb = ws[p][25];
    #pragma unroll
    for (int r = 0; r < 4; ++r) {
      float v0 = gelu_f(o0[r] + bb);
      float v1 = gelu_f(o1[r] + bb);
      if (ADD) {
        unsigned ctr = *(const unsigned*)(tp + (r + 2) * 68 + txp * 2 + 2);
        v0 += b2f_lo(ctr); v1 += b2f_hi(ctr);
      }
      res[pp][0][r] = f2b(v0); res[pp][1][r] = f2b(v1);
    }
  }
  #pragma unroll
  for (int r = 0; r < 4; ++r) {
    #pragma unroll
    for (int c = 0; c < 2; ++c) {
      const int pix = (by + r) * 192 + bx + txp * 2 + c;
      uint2 pk = make_uint2(
        (unsigned)res[0][c][r] | ((unsigned)res[1][c][r] << 16),
        (unsigned)res[2][c][r] | ((unsigned)res[3][c][r] << 16));
      *(uint2*)(out + (size_t)pix * PL + p0 + pg * 4) = pk;
    }
  }
}

// ---------- fused window attention v4 ----------
// rpb pre-fused into scores; select on unnormalized u=e*pfa (ordering-equiv);
// vJ [j][d] layout -> conflict-free AmV; vl TM -> coalesced epilogue.
__global__ __launch_bounds__(512, 4)
void attn_kernel(const u16* __restrict__ qg, const u16* __restrict__ kg,
                 const u16* __restrict__ vg, const u16* __restrict__ vlt,
                 const float* __restrict__ pfa_v, const int* __restrict__ pfa_i,
                 const float* __restrict__ rpbg, u16* __restrict__ attn_out)
{
  const int h = blockIdx.x;
  const int win = blockIdx.y;
  const int wy = (win / 12) * 16;
  const int wx = (win - (win / 12) * 12) * 16;
  const size_t hb = (size_t)h * HDIM * HW;

  __shared__ u16 kT[256 * 40];      // [j][d]  20480 B
  __shared__ u16 vJ[256 * 40];      // [j][d]  20480 B
  __shared__ float Sb[32 * 260];    //         33280 B
  __shared__ u16 qT[32 * 40];       // [i][d]   2560 B
  __shared__ float2 selbuf[8][64];  //          4096 B

  const int tid = threadIdx.x;
  const int lane = tid & 63, wave = tid >> 6;

  #pragma unroll
  for (int r = 0; r < 8; ++r) {
    int idx = tid + r * 512;
    int d = idx >> 7, jp = idx & 127, j = jp * 2;
    int pg = (wy + (j >> 4)) * 192 + (wx + (j & 15));
    ushort2 kv = *(const ushort2*)(kg + hb + (size_t)d * HW + pg);
    kT[j * 40 + d] = kv.x; kT[(j + 1) * 40 + d] = kv.y;
    ushort2 vv = *(const ushort2*)(vg + hb + (size_t)d * HW + pg);
    vJ[j * 40 + d] = vv.x; vJ[(j + 1) * 40 + d] = vv.y;
  }
  __syncthreads();

  const size_t wb = ((size_t)win * NH + h) * 256;
  const float* rpp = rpbg + (size_t)h * 65536;

  for (int pass = 0; pass < 8; ++pass) {
    {
      int d = tid >> 4, ip = tid & 15, i = pass * 32 + ip * 2;
      int pg = (wy + (i >> 4)) * 192 + (wx + (i & 15));
      ushort2 qv = *(const ushort2*)(qg + hb + (size_t)d * HW + pg);
      qT[(ip * 2) * 40 + d] = qv.x; qT[(ip * 2 + 1) * 40 + d] = qv.y;
    }
    __syncthreads();
    {
      const int it = wave & 1;
      const int fm = lane & 15, fq = lane >> 4;
      bf16x8 aq = *(const bf16x8*)&qT[(it * 16 + fm) * 40 + fq * 8];
      #pragma unroll
      for (int t = 0; t < 4; ++t) {
        int j0 = ((wave >> 1) * 4 + t) * 16;
        bf16x8 bk = *(const bf16x8*)&kT[(j0 + fm) * 40 + fq * 8];
        f32x4 c = __builtin_amdgcn_mfma_f32_16x16x32_bf16(aq, bk, (f32x4)(0.f), 0, 0, 0);
        const int col = j0 + fm, rowb = it * 16 + fq * 4;
        const int ib = pass * 32 + rowb;
        c[0] += rpp[(size_t)(ib + 0) * 256 + col];
        c[1] += rpp[(size_t)(ib + 1) * 256 + col];
        c[2] += rpp[(size_t)(ib + 2) * 256 + col];
        c[3] += rpp[(size_t)(ib + 3) * 256 + col];
        Sb[(rowb + 0) * 260 + col] = c[0]; Sb[(rowb + 1) * 260 + col] = c[1];
        Sb[(rowb + 2) * 260 + col] = c[2]; Sb[(rowb + 3) * 260 + col] = c[3];
      }
    }
    __syncthreads();
    int pj1[4], pj2[4]; float pv1[4], pv2[4];
    #pragma unroll
    for (int u = 0; u < 4; ++u) {
      const int i = pass * 32 + u * 8 + wave;
      const size_t base = (wb + (size_t)i) * 128;
      pj1[u] = pfa_i[base + lane];  pj2[u] = pfa_i[base + 64 + lane];
      pv1[u] = pfa_v[base + lane];  pv2[u] = pfa_v[base + 64 + lane];
    }
    #pragma unroll
    for (int u = 0; u < 4; ++u) {
      const int iq = u * 8 + wave;
      const int i  = pass * 32 + iq;
      const int j1 = pj1[u], j2 = pj2[u];
      float s1 = Sb[iq * 260 + j1];
      float s2 = Sb[iq * 260 + j2];
      float mx = fmaxf(s1, s2);
      #pragma unroll
      for (int o = 32; o > 0; o >>= 1) mx = fmaxf(mx, __shfl_xor(mx, o));
      float e1 = expf(s1 - mx), e2 = expf(s2 - mx);
      float u1 = e1 * pv1[u], u2 = e2 * pv2[u];
      // radix select on u (independent of reductions -> overlaps them)
      const unsigned ub1 = __float_as_uint(u1), ub2 = __float_as_uint(u2);
      unsigned thr = 0u;
      for (int bit = 30; bit >= 0; --bit) {
        unsigned cand = thr | (1u << bit);
        int cnt = (int)__popcll(__ballot(ub1 >= cand)) + (int)__popcll(__ballot(ub2 >= cand));
        if (cnt >= 64) { thr = cand; if (cnt == 64) break; }
      }
      float sA = e1 + e2, sB = u1 + u2;
      #pragma unroll
      for (int o = 32; o > 0; o >>= 1) { sA += __shfl_xor(sA, o); sB += __shfl_xor(sB, o); }
      const unsigned long long lmlt = (1ull << lane) - 1ull;
      const bool gt1 = ub1 > thr, gt2 = ub2 > thr;
      const bool eq1 = ub1 == thr, eq2 = ub2 == thr;
      const unsigned long long meq1 = __ballot(eq1), meq2 = __ballot(eq2);
      const int need = 64 - (int)__popcll(__ballot(gt1)) - (int)__popcll(__ballot(gt2));
      const bool sel1 = gt1 || (eq1 && (int)__popcll(meq1 & lmlt) < need);
      const bool sel2 = gt2 || (eq2 && ((int)__popcll(meq1) + (int)__popcll(meq2 & lmlt)) < need);
      const unsigned long long ms1 = __ballot(sel1), ms2 = __ballot(sel2);
      const int pos1 = (int)__popcll(ms1 & lmlt);
      const int pos2 = (int)__popcll(ms1) + (int)__popcll(ms2 & lmlt);
      const float t = 1e-10f * sA;
      const float rden = 1.0f / (sB + t);
      if (sel1) selbuf[wave][pos1] = make_float2((u1 + t) * rden, __int_as_float(j1));
      if (sel2) selbuf[wave][pos2] = make_float2((u2 + t) * rden, __int_as_float(j2));
      // sparse AmV: vJ [j][d] -> contiguous 64B gathers
      const int d = lane & 31, half = lane >> 5;
      float acc = 0.f;
      #pragma unroll
      for (int c = 0; c < 4; ++c) {
        float2 sv[8];
        #pragma unroll
        for (int q4 = 0; q4 < 4; ++q4)
          *(float4*)&sv[q4 * 2] = *(const float4*)&selbuf[wave][half * 32 + c * 8 + q4 * 2];
        #pragma unroll
        for (int s = 0; s < 8; ++s)
          acc = fmaf(sv[s].x, b2f(vJ[__float_as_int(sv[s].y) * 40 + d]), acc);
      }
      acc += __shfl_xor(acc, 32);
      const int pg = (wy + (i >> 4)) * 192 + (wx + (i & 15));
      if (lane < 32) {
        float o = acc + b2f(vlt[(size_t)pg * CD + h * HDIM + d]);
        attn_out[(size_t)pg * CD + h * HDIM + d] = f2b(o);
      }
    }
    __syncthreads();
  }
}

// ---------- launch ----------
extern "C" void kernel_launch(void* const* d_in, const int* in_sizes, int n_in,
                              void* d_out, int out_size, void* d_ws, size_t ws_size,
                              hipStream_t stream)
{
  (void)in_sizes; (void)n_in; (void)out_size; (void)ws_size;
  const float* features = (const float*)d_in[0];
  const float* pfa_v    = (const float*)d_in[1];
  const int*   pfa_i    = (const int*)d_in[2];
  const int*   rpi      = (const int*)d_in[3];
  const float* ln1_g    = (const float*)d_in[4];
  const float* ln1_b    = (const float*)d_in[5];
  const float* Wq_w     = (const float*)d_in[6];
  const float* Wq_b     = (const float*)d_in[7];
  const float* Wk_w     = (const float*)d_in[8];
  const float* Wk_b     = (const float*)d_in[9];
  const float* Wv_w     = (const float*)d_in[10];
  const float* Wv_b     = (const float*)d_in[11];
  const float* lepe_w   = (const float*)d_in[12];
  const float* lepe_b   = (const float*)d_in[13];
  const float* rpb_t    = (const float*)d_in[14];
  const float* proj_w   = (const float*)d_in[15];
  const float* proj_b   = (const float*)d_in[16];
  const float* ln2_g    = (const float*)d_in[17];
  const float* ln2_b    = (const float*)d_in[18];
  const float* fc1_w    = (const float*)d_in[19];
  const float* fc1_b    = (const float*)d_in[20];
  const float* dw_w     = (const float*)d_in[21];
  const float* dw_b     = (const float*)d_in[22];
  const float* fc2_w    = (const float*)d_in[23];
  const float* fc2_b    = (const float*)d_in[24];

  char* ws = (char*)d_ws;
  const size_t S  = (size_t)HW * CD;
  const size_t SB = S * 4;
  u16*   xnt    = (u16*)(ws);                         // bf16 TM
  u16*   qkvb   = (u16*)(ws + SB / 2);                // bf16 CM q(scaled),k,v
  u16*   q_ = qkvb; u16* k_ = qkvb + S; u16* v_ = qkvb + 2 * S;
  u16*   vlt    = (u16*)(ws + 2 * SB);                // bf16 TM [HW][192]
  u16*   attn_o = (u16*)(ws + 2 * SB + SB / 2);       // bf16 TM
  float* x2     = (float*)(ws + 3 * SB);              // fp32 CM, live to end
  u16*   xn2t   = (u16*)(ws + 4 * SB);                // bf16 TM
  u16*   y_     = (u16*)(ws + 4 * SB + SB / 2);       // bf16 CM [768][HW]
  u16*   y2t    = (u16*)(ws + 6 * SB + SB / 2);       // bf16 TM [HW][768]
  u16*   wqt  = (u16*)(ws + 8 * SB + SB / 2);
  u16*   wkt  = wqt + 36864;
  u16*   wvt  = wkt + 36864;
  u16*   wpt  = wvt + 36864;
  u16*   wf1t = wpt + 36864;      // [768][192]
  u16*   wf2t = wf1t + 147456;    // [192][768]
  float* rpbg = (float*)(wf2t + 147456 + 128);
  float* out = (float*)d_out;

  // 0) weight prep + rpb pre-gather
  wtrans4_kernel<<<dim3(6, 6, 4), 256, 0, stream>>>(Wq_w, Wk_w, Wv_w, proj_w, wqt);
  wtrans_kernel<<<dim3(6, 24), 256, 0, stream>>>(fc1_w, wf1t, 192, 768);
  wtrans_kernel<<<dim3(24, 6), 256, 0, stream>>>(fc2_w, wf2t, 768, 192);
  rpbg_kernel<<<dim3(256), 256, 0, stream>>>(rpi, rpb_t, rpbg);
  // 1) LN1 fused transpose
  lnt_kernel<<<dim3(HW / 64), 256, 0, stream>>>(features, ln1_g, ln1_b, xnt);
  // 2) QKV MFMA -> bf16 CM (q scaled)
  mgemm_kernel<0><<<dim3(9, HW / 128), 256, 0, stream>>>(xnt, wqt, wkt, wvt, Wq_b, Wk_b, Wv_b,
                                                         nullptr, qkvb, 192, 192);
  // 3) LePE dwconv on v -> bf16 TM
  dwconv_tm_kernel<false><<<dim3(3, 48, 6), 256, 0, stream>>>(v_, lepe_w, lepe_b, vlt, CD);
  // 4) window attention -> bf16 TM
  attn_kernel<<<dim3(6, 144), 512, 0, stream>>>(q_, k_, v_, vlt, pfa_v, pfa_i, rpbg, attn_o);
  // 5) proj + shortcut -> fp32 CM x2
  mgemm_kernel<1><<<dim3(3, HW / 128), 256, 0, stream>>>(attn_o, wpt, wpt, wpt, proj_b, proj_b, proj_b,
                                                         features, x2, 192, 1 << 30);
  // 6) LN2 fused transpose
  lnt_kernel<<<dim3(HW / 64), 256, 0, stream>>>(x2, ln2_g, ln2_b, xn2t);
  // 7) fc1 + GELU -> bf16 CM y
  mgemm_kernel<2><<<dim3(12, HW / 128), 256, 0, stream>>>(xn2t, wf1t, wf1t, wf1t, fc1_b, fc1_b, fc1_b,
                                                          nullptr, y_, 192, 1 << 30);
  // 8) y2 = y + gelu(dwconv(y)+b) -> bf16 TM (transpose fused)
  dwconv_tm_kernel<true><<<dim3(3, 48, 24), 256, 0, stream>>>(y_, dw_w, dw_b, y2t, HIDD);
  // 9) fc2 + x2 residual -> fp32 TM final output
  mgemm_kernel<3><<<dim3(3, HW / 128), 256, 0, stream>>>(y2t, wf2t, wf2t, wf2t, fc2_b, fc2_b, fc2_b,
                                                         x2, out, 768, 1 << 30);
}